// Round 4
// baseline (143.595 us; speedup 1.0000x reference)
//
#include <hip/hip_runtime.h>

#define BATCH 100000

typedef float v2 __attribute__((ext_vector_type(2)));

__device__ __forceinline__ v2 fma2(v2 a, v2 b, v2 c) { return __builtin_elementwise_fma(a, b, c); }
__device__ __forceinline__ v2 relu2(v2 a) { v2 z = {0.f, 0.f}; return __builtin_elementwise_max(a, z); }
__device__ __forceinline__ v2 splat(float a) { v2 r = {a, a}; return r; }
__device__ __forceinline__ v2 ldv2(const float* p) { return *(const v2*)p; }

// R12: one SAMPLE PER LANE (t-split removed), x staged in LDS.
// R8 vs R11 post-mortem: time invariant (56 vs 52 us) because SMEM
// dwords per sample-unit was invariant (134 vs 131): weight s_loads are
// wave-broadcast, the 34 KB weight set thrashes the scalar cache, and
// each W2 row-batch miss (~250 cy to L2) has only ~128 cy of dependent
// compute to hide under. Lever: samples/wave. Here each lane owns a
// full sample; wave h owns hidden [32h,32h+32) -> 64 samples on the
// same 2.1k-dword wave stream = 65 dw/unit (2x cut), and latency
// amortizes over 2x compute. Bonus: t-duplication of W2/rho/psi gone
// (executed MACs/sample 12.3k -> 8.7k), barrier term lane-local (no
// shuffles), final store fully coalesced.
// x rows staged in LDS via coalesced dword copy (kills the 42-84
// uncoalesced VMEM/thread pattern); rows padded to stride 88 dw,
// payload at +3 so nb (elem 5) and ob (elem 69) are 16B-aligned for
// ds_read_b128.
// Block 128 = 1 wave-pair = 64 samples; LDS 22528 B -> 7 blocks/CU cap;
// grid 1563 ~ 6.1/CU -> whole grid co-resident. launch_bounds(128,3):
// VGPR cap ~170 for nb[16][4]=64 regs (spill tripwire: WRITE_SIZE,
// R3/R6/R9). Weight bases via readfirstlane(h) -- MUST keep (R11: without
// it every weight read becomes per-lane VMEM and scratch explodes).
__global__ __launch_bounds__(128, 3) void barrier_net(
    const float* __restrict__ x,
    const float* __restrict__ phi_w1, const float* __restrict__ phi_b1,
    const float* __restrict__ phi_w2, const float* __restrict__ phi_b2,
    const float* __restrict__ obs_w1, const float* __restrict__ obs_b1,
    const float* __restrict__ obs_w2, const float* __restrict__ obs_b2,
    const float* __restrict__ rho_w1, const float* __restrict__ rho_b1,
    const float* __restrict__ rho_w2, const float* __restrict__ rho_b2,
    const float* __restrict__ psi_w1, const float* __restrict__ psi_b1,
    const float* __restrict__ psi_w2, const float* __restrict__ psi_b2,
    float2* __restrict__ out)
{
    // xs: 64 rows x stride 88, payload at +3. After sync2 the front of
    // this buffer is reused for the h-combine scratch:
    //   accS: dwords [0, 2304)  = [2][64][18] (stride 18 = conflict-free)
    //   rrS : dwords [2304,2560) = [2][64][2]
    //   eeS : dwords [2560,2688) = [64][2]
    __shared__ float L[64 * 88];

    const int lane = threadIdx.x & 63;
    const int h    = threadIdx.x >> 6;                     // 2 waves/block
    const int hu   = __builtin_amdgcn_readfirstlane(h);    // scalar fact
    const int base = blockIdx.x * 64;

    // ---- coalesced x staging: 64 rows x 85 dw, clamped tail ----
    for (int d = threadIdx.x; d < 64 * 85; d += 128) {
        unsigned r = (unsigned)d / 85u;        // magic-mul div
        int e  = d - (int)r * 85;
        int rg = base + (int)r;
        if (rg > BATCH - 1) rg = BATCH - 1;
        L[(int)r * 88 + 3 + e] = x[(size_t)rg * 85 + e];
    }
    __syncthreads();                                        // sync1

    int s = base + lane;
    const bool valid = (s < BATCH);
    if (!valid) s = BATCH - 1;                              // staged row matches clamp
    const float* xr = L + lane * 88 + 3;

    // ---- uniform hidden-slice base pointers (R11 scheme) ----
    const int HB = hu * 32;
    const float* pw1 = phi_w1 + HB;                 // row stride 64
    const float* pb1 = phi_b1 + HB;
    const float* pw2 = phi_w2 + (size_t)HB * 16;    // W2 row slice
    const float* qw1 = obs_w1 + HB;
    const float* qb1 = obs_b1 + HB;
    const float* qw2 = obs_w2 + (size_t)HB * 16;
    const float* rw1 = rho_w1 + HB;                 // row stride 64
    const float* rb1 = rho_b1 + HB;
    const float* rw2 = rho_w2 + (size_t)HB * 2;
    const float* sw1 = psi_w1 + HB;
    const float* sb1 = psi_b1 + HB;
    const float* sw2 = psi_w2 + (size_t)HB * 2;

    const float g0 = xr[0], g1 = xr[1];

    // ---- all 16 neighbors, ds_read_b128 (16B-aligned by the +3 pad) ----
    float nb[16][4];
#pragma unroll
    for (int n = 0; n < 16; ++n) {
        float4 q = *(const float4*)(xr + 5 + 4 * n);
        nb[n][0] = q.x; nb[n][1] = q.y; nb[n][2] = q.z; nb[n][3] = q.w;
    }

    // ---- barrier term: lane-local over all 16 neighbors (h0 only) ----
    float bar0 = 0.f, bar1 = 0.f;
    if (hu == 0) {
#pragma unroll
        for (int n = 0; n < 16; ++n) {
            float p0 = -nb[n][0], p1 = -nb[n][1];
            float r  = __builtin_amdgcn_sqrtf(fmaf(p0, p0, p1 * p1));
            float sc = 0.01f * __builtin_amdgcn_rcpf(r - 0.2f);
            bar0 = fmaf(sc, p0, bar0);
            bar1 = fmaf(sc, p1, bar1);
        }
    }

    // ---- acc: full 16 outputs per lane; h0 carries the biases ----
    v2 acc[8];
#pragma unroll
    for (int p = 0; p < 8; ++p) acc[p] = splat(0.f);
    if (hu == 0) {
#pragma unroll
        for (int p = 0; p < 8; ++p)
            acc[p] = fma2(splat(16.f), ldv2(phi_b2 + 2 * p),
                     fma2(splat(8.f),  ldv2(obs_b2 + 2 * p), splat(0.f)));
    }

    // ---- phi: 4 chunks of 8 hidden, all 16 neighbors ----
#pragma unroll 2
    for (int c = 0; c < 4; ++c) {
        const int hb = 8 * c;
        v2 hsv[4] = {{0.f,0.f},{0.f,0.f},{0.f,0.f},{0.f,0.f}};
#pragma unroll
        for (int n = 0; n < 16; ++n) {
#pragma unroll
            for (int p = 0; p < 4; ++p) {
                v2 tv = fma2(splat(nb[n][0]), ldv2(pw1 + hb + 2 * p),
                        fma2(splat(nb[n][1]), ldv2(pw1 + 64 + hb + 2 * p),
                        fma2(splat(nb[n][2]), ldv2(pw1 + 128 + hb + 2 * p),
                        fma2(splat(nb[n][3]), ldv2(pw1 + 192 + hb + 2 * p),
                                              ldv2(pb1 + hb + 2 * p)))));
                hsv[p] += relu2(tv);
            }
        }
#pragma unroll
        for (int p = 0; p < 4; ++p) {
            const float* r0 = pw2 + (size_t)(hb + 2 * p) * 16;
            v2 hx = splat(hsv[p].x), hy = splat(hsv[p].y);
#pragma unroll
            for (int q = 0; q < 8; ++q)
                acc[q] = fma2(hy, ldv2(r0 + 16 + 2 * q),
                         fma2(hx, ldv2(r0 + 2 * q), acc[q]));
        }
    }

    // ---- all 8 observations (read from LDS after phi: lower reg peak) ----
    float ob[8][2];
#pragma unroll
    for (int i = 0; i < 4; ++i) {
        float4 q = *(const float4*)(xr + 69 + 4 * i);
        ob[2 * i][0]     = q.x; ob[2 * i][1]     = q.y;
        ob[2 * i + 1][0] = q.z; ob[2 * i + 1][1] = q.w;
    }

    // ---- obs: same chunking, 8 observations ----
#pragma unroll 2
    for (int c = 0; c < 4; ++c) {
        const int hb = 8 * c;
        v2 hsv[4] = {{0.f,0.f},{0.f,0.f},{0.f,0.f},{0.f,0.f}};
#pragma unroll
        for (int o = 0; o < 8; ++o) {
#pragma unroll
            for (int p = 0; p < 4; ++p) {
                v2 tv = fma2(splat(ob[o][0]), ldv2(qw1 + hb + 2 * p),
                        fma2(splat(ob[o][1]), ldv2(qw1 + 64 + hb + 2 * p),
                                              ldv2(qb1 + hb + 2 * p)));
                hsv[p] += relu2(tv);
            }
        }
#pragma unroll
        for (int p = 0; p < 4; ++p) {
            const float* r0 = qw2 + (size_t)(hb + 2 * p) * 16;
            v2 hx = splat(hsv[p].x), hy = splat(hsv[p].y);
#pragma unroll
            for (int q = 0; q < 8; ++q)
                acc[q] = fma2(hy, ldv2(r0 + 16 + 2 * q),
                         fma2(hx, ldv2(r0 + 2 * q), acc[q]));
        }
    }

    __syncthreads();   // sync2: all LDS x-reads done; safe to reuse L

    // ---- combine acc across the wave pair (stride-18: conflict-free) ----
    {
        float* slot = L + (h * 64 + lane) * 18;
#pragma unroll
        for (int p = 0; p < 8; ++p)
            *(v2*)(slot + 2 * p) = acc[p];
    }
    __syncthreads();   // sync3
    {
        const float* oslot = L + ((h ^ 1) * 64 + lane) * 18;
#pragma unroll
        for (int p = 0; p < 8; ++p)
            acc[p] += ldv2(oslot + 2 * p);
    }

    // ---- rho: 16 -> hidden slice -> 2 (partial) ----
    v2 rr = (hu == 0) ? ldv2(rho_b2) : splat(0.f);
#pragma unroll 2
    for (int c = 0; c < 4; ++c) {
        const int hb = 8 * c;
        v2 tt[4];
#pragma unroll
        for (int p = 0; p < 4; ++p)
            tt[p] = ldv2(rb1 + hb + 2 * p);
#pragma unroll
        for (int j = 0; j < 8; ++j) {
            v2 ax = splat(acc[j].x), ay = splat(acc[j].y);
            const float* rj0 = rw1 + (size_t)(2 * j) * 64 + hb;
            const float* rj1 = rw1 + (size_t)(2 * j + 1) * 64 + hb;
#pragma unroll
            for (int p = 0; p < 4; ++p)
                tt[p] = fma2(ay, ldv2(rj1 + 2 * p),
                        fma2(ax, ldv2(rj0 + 2 * p), tt[p]));
        }
#pragma unroll
        for (int p = 0; p < 4; ++p) {
            v2 u = relu2(tt[p]);
            rr = fma2(splat(u.x), ldv2(rw2 + 2 * (hb + 2 * p)), rr);
            rr = fma2(splat(u.y), ldv2(rw2 + 2 * (hb + 2 * p) + 2), rr);
        }
    }
    *(v2*)(L + 2304 + (h * 64 + lane) * 2) = rr;
    __syncthreads();   // sync4
    rr += ldv2(L + 2304 + ((h ^ 1) * 64 + lane) * 2);

    // ---- psi: [r0, r1, g0, g1] -> hidden slice -> 2 (partial) ----
    v2 ee = (hu == 0) ? ldv2(psi_b2) : splat(0.f);
#pragma unroll 2
    for (int c = 0; c < 4; ++c) {
        const int hb = 8 * c;
#pragma unroll
        for (int p = 0; p < 4; ++p) {
            v2 tv = fma2(splat(rr.x), ldv2(sw1 + hb + 2 * p),
                    fma2(splat(rr.y), ldv2(sw1 + 64 + hb + 2 * p),
                    fma2(splat(g0),   ldv2(sw1 + 128 + hb + 2 * p),
                    fma2(splat(g1),   ldv2(sw1 + 192 + hb + 2 * p),
                                      ldv2(sb1 + hb + 2 * p)))));
            v2 u = relu2(tv);
            ee = fma2(splat(u.x), ldv2(sw2 + 2 * (hb + 2 * p)), ee);
            ee = fma2(splat(u.y), ldv2(sw2 + 2 * (hb + 2 * p) + 2), ee);
        }
    }
    if (hu == 1)
        *(v2*)(L + 2560 + lane * 2) = ee;
    __syncthreads();   // sync5

    if (hu == 0 && valid) {
        v2 eo = ldv2(L + 2560 + lane * 2);
        float a0 = tanhf(tanhf(ee.x + eo.x) + bar0);
        float a1 = tanhf(tanhf(ee.y + eo.y) + bar1);
        out[s] = make_float2(2.f * a0, 2.f * a1);   // coalesced across lanes
    }
}

extern "C" void kernel_launch(void* const* d_in, const int* in_sizes, int n_in,
                              void* d_out, int out_size, void* d_ws, size_t ws_size,
                              hipStream_t stream) {
    dim3 grid((BATCH + 63) / 64), block(128);   // 64 samples per block
    barrier_net<<<grid, block, 0, stream>>>(
        (const float*)d_in[0],
        (const float*)d_in[1],  (const float*)d_in[2],  (const float*)d_in[3],  (const float*)d_in[4],
        (const float*)d_in[5],  (const float*)d_in[6],  (const float*)d_in[7],  (const float*)d_in[8],
        (const float*)d_in[9],  (const float*)d_in[10], (const float*)d_in[11], (const float*)d_in[12],
        (const float*)d_in[13], (const float*)d_in[14], (const float*)d_in[15], (const float*)d_in[16],
        (float2*)d_out);
}